// Round 1
// baseline (1384.001 us; speedup 1.0000x reference)
//
#include <hip/hip_runtime.h>

// Problem constants (from reference)
constexpr int N_PART = 100000;
constexpr int N_EDGE = 6400000;
constexpr float SUPPORT = 0.05f;

// Zero both the normals workspace and the output (harness poisons with 0xAA).
__global__ __launch_bounds__(256) void zero2_kernel(float* __restrict__ a,
                                                    float* __restrict__ b, int n) {
    int idx = blockIdx.x * blockDim.x + threadIdx.x;
    if (idx < n) {
        a[idx] = 0.0f;
        b[idx] = 0.0f;
    }
}

// Pass 1: normals[i] += SUPPORT * (areas[j]/dens[j]) * dWdq(q) * dist
__global__ __launch_bounds__(256) void pass1_normals(
    const int* __restrict__ nb,        // [2*E]: row0 = i, row1 = j
    const float* __restrict__ areas,   // [N]
    const float* __restrict__ dens,    // [N]
    const float* __restrict__ q,       // [E]
    const float2* __restrict__ dist,   // [E] (x,y)
    float* __restrict__ normals)       // [N*2]
{
    int e = blockIdx.x * blockDim.x + threadIdx.x;
    if (e >= N_EDGE) return;
    int i = nb[e];
    int j = nb[N_EDGE + e];

    float qq  = q[e];
    float fac = areas[j] / dens[j];

    // 2D Wendland C2 gradient magnitude: C = 7/(pi h^2); dWdq = C*(-20 q (1-q)^3)/h
    const float C = 7.0f / (3.14159265358979323846f * SUPPORT * SUPPORT);
    float omq  = fmaxf(1.0f - qq, 0.0f);
    float dWdq = C * (-20.0f * qq * omq * omq * omq) * (1.0f / SUPPORT);

    float s = SUPPORT * fac * dWdq;
    float2 d = dist[e];

    atomicAdd(&normals[2 * i],     s * d.x);
    atomicAdd(&normals[2 * i + 1], s * d.y);
}

// Pass 2: out[i] += -(normals[i] - normals[j]) + areas[j]*rest[j]*kern(q)*dist
// (cohesion_kernel returns -where(...); cohesion multiplies by -GAMMA=-1 -> net +)
__global__ __launch_bounds__(256) void pass2_forces(
    const int* __restrict__ nb,
    const float* __restrict__ areas,
    const float* __restrict__ rest,
    const float* __restrict__ q,
    const float2* __restrict__ dist,
    const float2* __restrict__ normals,  // [N] as float2
    float* __restrict__ out)             // [N*2]
{
    int e = blockIdx.x * blockDim.x + threadIdx.x;
    if (e >= N_EDGE) return;
    int i = nb[e];
    int j = nb[N_EDGE + e];

    float2 ni = normals[i];
    float2 nj = normals[j];

    float qq  = q[e];
    float fc  = areas[j] * rest[j];
    float qm1 = qq - 1.0f;
    float t   = qm1 * qm1 * qm1 * qq * qq * qq;   // (q-1)^3 q^3
    float kern = (qq <= 0.5f) ? fmaf(128.0f, t, 1.0f) : 64.0f * t;

    float2 d = dist[e];
    float cx = -(ni.x - nj.x) + fc * kern * d.x;
    float cy = -(ni.y - nj.y) + fc * kern * d.y;

    atomicAdd(&out[2 * i],     cx);
    atomicAdd(&out[2 * i + 1], cy);
}

extern "C" void kernel_launch(void* const* d_in, const int* in_sizes, int n_in,
                              void* d_out, int out_size, void* d_ws, size_t ws_size,
                              hipStream_t stream) {
    const int*   nb    = (const int*)d_in[0];     // [2*E]
    const float* areas = (const float*)d_in[1];   // [N]
    const float* dens  = (const float*)d_in[2];   // [N]
    const float* rest  = (const float*)d_in[3];   // [N]
    const float* q     = (const float*)d_in[4];   // [E]
    const float* dist  = (const float*)d_in[5];   // [E,2]
    float* out = (float*)d_out;                   // [N,2]

    float* normals = (float*)d_ws;                // [N*2] floats (800 KB)

    const int nv = 2 * N_PART;
    zero2_kernel<<<(nv + 255) / 256, 256, 0, stream>>>(normals, out, nv);

    const int blocks = (N_EDGE + 255) / 256;
    pass1_normals<<<blocks, 256, 0, stream>>>(
        nb, areas, dens, q, (const float2*)dist, normals);
    pass2_forces<<<blocks, 256, 0, stream>>>(
        nb, areas, rest, q, (const float2*)dist, (const float2*)normals, out);
}

// Round 2
// 1382.147 us; speedup vs baseline: 1.0013x; 1.0013x over previous
//
#include <hip/hip_runtime.h>

// Problem constants (from reference)
constexpr int N_PART = 100000;
constexpr int N_EDGE = 6400000;
constexpr float SUPPORT = 0.05f;

typedef float v2f __attribute__((ext_vector_type(2)));

// Packed 2xfp32 global atomic add (gfx90a+: global_atomic_pk_add_f32).
// One 8B RMW transaction instead of two 4B ones — halves atomic traffic.
// addr must be 8B-aligned (guaranteed: index 2*i on an 8B-aligned base).
__device__ inline void atomic_add2(float* addr, float x, float y) {
#if __has_builtin(__builtin_amdgcn_global_atomic_fadd_v2f32)
    v2f v = {x, y};
    __builtin_amdgcn_global_atomic_fadd_v2f32(
        (v2f __attribute__((address_space(1)))*)(unsigned long long)addr, v);
#else
    atomicAdd(addr, x);
    atomicAdd(addr + 1, y);
#endif
}

// Zero both the normals workspace and the output (harness poisons with 0xAA).
__global__ __launch_bounds__(256) void zero2_kernel(float* __restrict__ a,
                                                    float* __restrict__ b, int n) {
    int idx = blockIdx.x * blockDim.x + threadIdx.x;
    if (idx < n) {
        a[idx] = 0.0f;
        b[idx] = 0.0f;
    }
}

// Pass 1: normals[i] += SUPPORT * (areas[j]/dens[j]) * dWdq(q) * dist
__global__ __launch_bounds__(256) void pass1_normals(
    const int* __restrict__ nb,        // [2*E]: row0 = i, row1 = j
    const float* __restrict__ areas,   // [N]
    const float* __restrict__ dens,    // [N]
    const float* __restrict__ q,       // [E]
    const float2* __restrict__ dist,   // [E] (x,y)
    float* __restrict__ normals)       // [N*2]
{
    int e = blockIdx.x * blockDim.x + threadIdx.x;
    if (e >= N_EDGE) return;
    int i = nb[e];
    int j = nb[N_EDGE + e];

    float qq  = q[e];
    float fac = areas[j] / dens[j];

    // 2D Wendland C2 gradient magnitude: C = 7/(pi h^2); dWdq = C*(-20 q (1-q)^3)/h
    const float C = 7.0f / (3.14159265358979323846f * SUPPORT * SUPPORT);
    float omq  = fmaxf(1.0f - qq, 0.0f);
    float dWdq = C * (-20.0f * qq * omq * omq * omq) * (1.0f / SUPPORT);

    float s = SUPPORT * fac * dWdq;
    float2 d = dist[e];

    atomic_add2(&normals[2 * i], s * d.x, s * d.y);
}

// Pass 2: out[i] += -(normals[i] - normals[j]) + areas[j]*rest[j]*kern(q)*dist
// (cohesion_kernel returns -where(...); cohesion multiplies by -GAMMA=-1 -> net +)
__global__ __launch_bounds__(256) void pass2_forces(
    const int* __restrict__ nb,
    const float* __restrict__ areas,
    const float* __restrict__ rest,
    const float* __restrict__ q,
    const float2* __restrict__ dist,
    const float2* __restrict__ normals,  // [N] as float2
    float* __restrict__ out)             // [N*2]
{
    int e = blockIdx.x * blockDim.x + threadIdx.x;
    if (e >= N_EDGE) return;
    int i = nb[e];
    int j = nb[N_EDGE + e];

    float2 ni = normals[i];
    float2 nj = normals[j];

    float qq  = q[e];
    float fc  = areas[j] * rest[j];
    float qm1 = qq - 1.0f;
    float t   = qm1 * qm1 * qm1 * qq * qq * qq;   // (q-1)^3 q^3
    float kern = (qq <= 0.5f) ? fmaf(128.0f, t, 1.0f) : 64.0f * t;

    float2 d = dist[e];
    float cx = -(ni.x - nj.x) + fc * kern * d.x;
    float cy = -(ni.y - nj.y) + fc * kern * d.y;

    atomic_add2(&out[2 * i], cx, cy);
}

extern "C" void kernel_launch(void* const* d_in, const int* in_sizes, int n_in,
                              void* d_out, int out_size, void* d_ws, size_t ws_size,
                              hipStream_t stream) {
    const int*   nb    = (const int*)d_in[0];     // [2*E]
    const float* areas = (const float*)d_in[1];   // [N]
    const float* dens  = (const float*)d_in[2];   // [N]
    const float* rest  = (const float*)d_in[3];   // [N]
    const float* q     = (const float*)d_in[4];   // [E]
    const float* dist  = (const float*)d_in[5];   // [E,2]
    float* out = (float*)d_out;                   // [N,2]

    float* normals = (float*)d_ws;                // [N*2] floats (800 KB)

    const int nv = 2 * N_PART;
    zero2_kernel<<<(nv + 255) / 256, 256, 0, stream>>>(normals, out, nv);

    const int blocks = (N_EDGE + 255) / 256;
    pass1_normals<<<blocks, 256, 0, stream>>>(
        nb, areas, dens, q, (const float2*)dist, normals);
    pass2_forces<<<blocks, 256, 0, stream>>>(
        nb, areas, rest, q, (const float2*)dist, (const float2*)normals, out);
}

// Round 3
// 631.512 us; speedup vs baseline: 2.1916x; 2.1886x over previous
//
#include <hip/hip_runtime.h>

// Problem constants (from reference)
constexpr int N_PART = 100000;
constexpr int N_EDGE = 6400000;
constexpr float SUPPORT = 0.05f;

// Binning: particles split into NBINS bins of BSZ (power of 2 -> bin = i>>13)
constexpr int BSZ_LOG2 = 13;
constexpr int BSZ   = 1 << BSZ_LOG2;          // 8192 particles/bin -> 64 KB LDS (x,y)
constexpr int NBINS = (N_PART + BSZ - 1) / BSZ; // 13
constexpr int NP_PAD = NBINS * BSZ;           // 106496 padded particle slots
constexpr int C_TARGET = 39;                  // edge chunks: grid = 13*39 = 507 blocks

// ---------------------------------------------------------------------------
// Binned pass 1: normals partials. Block (b,c): stream chunk c, filter i in
// bin b, accumulate in LDS (on-CU atomics), flush non-atomically to partials.
// ---------------------------------------------------------------------------
__global__ __launch_bounds__(1024) void pass1_binned(
    const int* __restrict__ nb,        // [2*E]
    const float* __restrict__ areas,   // [N]
    const float* __restrict__ dens,    // [N]
    const float* __restrict__ q,       // [E]
    const float2* __restrict__ dist,   // [E]
    float* __restrict__ partials,      // [C][NP_PAD][2]
    int C)
{
    __shared__ float lds[2 * BSZ];     // 64 KB

    const int b = blockIdx.x % NBINS;
    const int c = blockIdx.x / NBINS;

    for (int k = threadIdx.x; k < 2 * BSZ; k += blockDim.x) lds[k] = 0.0f;
    __syncthreads();

    const int start = (int)((long long)c       * (N_EDGE / 4) / C) * 4;
    const int end   = (int)((long long)(c + 1) * (N_EDGE / 4) / C) * 4;

    const int4* __restrict__ nb4 = (const int4*)nb;
    const float Cw = 7.0f / (3.14159265358979323846f * SUPPORT * SUPPORT);

    for (int e = start + (int)threadIdx.x * 4; e < end; e += (int)blockDim.x * 4) {
        int4 iq = nb4[e >> 2];
        #pragma unroll
        for (int k = 0; k < 4; ++k) {
            int iv = (k == 0) ? iq.x : (k == 1) ? iq.y : (k == 2) ? iq.z : iq.w;
            if ((iv >> BSZ_LOG2) == b) {
                int ee = e + k;
                int j  = nb[N_EDGE + ee];
                float qq  = q[ee];
                float fac = areas[j] / dens[j];
                float omq  = fmaxf(1.0f - qq, 0.0f);
                float dWdq = Cw * (-20.0f * qq * omq * omq * omq) * (1.0f / SUPPORT);
                float s = SUPPORT * fac * dWdq;
                float2 d = dist[ee];
                int loc = (iv & (BSZ - 1)) << 1;
                atomicAdd(&lds[loc],     s * d.x);
                atomicAdd(&lds[loc + 1], s * d.y);
            }
        }
    }
    __syncthreads();

    // Non-atomic coalesced flush of this block's bin
    float2* __restrict__ dst = (float2*)partials + (size_t)c * NP_PAD + (size_t)b * BSZ;
    const float2* __restrict__ src = (const float2*)lds;
    for (int k = threadIdx.x; k < BSZ; k += blockDim.x) dst[k] = src[k];
}

// ---------------------------------------------------------------------------
// Binned pass 2: curvature + cohesion partials.
// per-edge: -(normals[i]-normals[j]) + areas[j]*rest[j]*kern(q)*dist
// ---------------------------------------------------------------------------
__global__ __launch_bounds__(1024) void pass2_binned(
    const int* __restrict__ nb,
    const float* __restrict__ areas,
    const float* __restrict__ rest,
    const float* __restrict__ q,
    const float2* __restrict__ dist,
    const float2* __restrict__ normals,  // [N]
    float* __restrict__ partials,        // [C][NP_PAD][2]
    int C)
{
    __shared__ float lds[2 * BSZ];

    const int b = blockIdx.x % NBINS;
    const int c = blockIdx.x / NBINS;

    for (int k = threadIdx.x; k < 2 * BSZ; k += blockDim.x) lds[k] = 0.0f;
    __syncthreads();

    const int start = (int)((long long)c       * (N_EDGE / 4) / C) * 4;
    const int end   = (int)((long long)(c + 1) * (N_EDGE / 4) / C) * 4;

    const int4* __restrict__ nb4 = (const int4*)nb;

    for (int e = start + (int)threadIdx.x * 4; e < end; e += (int)blockDim.x * 4) {
        int4 iq = nb4[e >> 2];
        #pragma unroll
        for (int k = 0; k < 4; ++k) {
            int iv = (k == 0) ? iq.x : (k == 1) ? iq.y : (k == 2) ? iq.z : iq.w;
            if ((iv >> BSZ_LOG2) == b) {
                int ee = e + k;
                int j  = nb[N_EDGE + ee];
                float2 ni = normals[iv];
                float2 nj = normals[j];
                float qq  = q[ee];
                float fc  = areas[j] * rest[j];
                float qm1 = qq - 1.0f;
                float t   = qm1 * qm1 * qm1 * qq * qq * qq;
                float kern = (qq <= 0.5f) ? fmaf(128.0f, t, 1.0f) : 64.0f * t;
                float2 d = dist[ee];
                int loc = (iv & (BSZ - 1)) << 1;
                atomicAdd(&lds[loc],     -(ni.x - nj.x) + fc * kern * d.x);
                atomicAdd(&lds[loc + 1], -(ni.y - nj.y) + fc * kern * d.y);
            }
        }
    }
    __syncthreads();

    float2* __restrict__ dst = (float2*)partials + (size_t)c * NP_PAD + (size_t)b * BSZ;
    const float2* __restrict__ src = (const float2*)lds;
    for (int k = threadIdx.x; k < BSZ; k += blockDim.x) dst[k] = src[k];
}

// dst[p] = sum_c partials[c][p] — owner-exclusive, no atomics, coalesced.
__global__ __launch_bounds__(256) void reduce_partials(
    const float* __restrict__ partials, float* __restrict__ dst, int C)
{
    int p = blockIdx.x * blockDim.x + threadIdx.x;
    if (p >= N_PART) return;
    const float2* __restrict__ p2 = (const float2*)partials;
    float ax = 0.0f, ay = 0.0f;
    for (int c = 0; c < C; ++c) {
        float2 v = p2[(size_t)c * NP_PAD + p];
        ax += v.x;
        ay += v.y;
    }
    ((float2*)dst)[p] = make_float2(ax, ay);
}

// ---------------------------------------------------------------------------
// Fallback (atomic) path, used only if ws_size is too small for partials.
// ---------------------------------------------------------------------------
__global__ __launch_bounds__(256) void zero2_kernel(float* __restrict__ a,
                                                    float* __restrict__ b, int n) {
    int idx = blockIdx.x * blockDim.x + threadIdx.x;
    if (idx < n) { a[idx] = 0.0f; b[idx] = 0.0f; }
}

__global__ __launch_bounds__(256) void pass1_atomic(
    const int* __restrict__ nb, const float* __restrict__ areas,
    const float* __restrict__ dens, const float* __restrict__ q,
    const float2* __restrict__ dist, float* __restrict__ normals)
{
    int e = blockIdx.x * blockDim.x + threadIdx.x;
    if (e >= N_EDGE) return;
    int i = nb[e];
    int j = nb[N_EDGE + e];
    float qq  = q[e];
    float fac = areas[j] / dens[j];
    const float C = 7.0f / (3.14159265358979323846f * SUPPORT * SUPPORT);
    float omq  = fmaxf(1.0f - qq, 0.0f);
    float dWdq = C * (-20.0f * qq * omq * omq * omq) * (1.0f / SUPPORT);
    float s = SUPPORT * fac * dWdq;
    float2 d = dist[e];
    atomicAdd(&normals[2 * i],     s * d.x);
    atomicAdd(&normals[2 * i + 1], s * d.y);
}

__global__ __launch_bounds__(256) void pass2_atomic(
    const int* __restrict__ nb, const float* __restrict__ areas,
    const float* __restrict__ rest, const float* __restrict__ q,
    const float2* __restrict__ dist, const float2* __restrict__ normals,
    float* __restrict__ out)
{
    int e = blockIdx.x * blockDim.x + threadIdx.x;
    if (e >= N_EDGE) return;
    int i = nb[e];
    int j = nb[N_EDGE + e];
    float2 ni = normals[i];
    float2 nj = normals[j];
    float qq  = q[e];
    float fc  = areas[j] * rest[j];
    float qm1 = qq - 1.0f;
    float t   = qm1 * qm1 * qm1 * qq * qq * qq;
    float kern = (qq <= 0.5f) ? fmaf(128.0f, t, 1.0f) : 64.0f * t;
    float2 d = dist[e];
    atomicAdd(&out[2 * i],     -(ni.x - nj.x) + fc * kern * d.x);
    atomicAdd(&out[2 * i + 1], -(ni.y - nj.y) + fc * kern * d.y);
}

extern "C" void kernel_launch(void* const* d_in, const int* in_sizes, int n_in,
                              void* d_out, int out_size, void* d_ws, size_t ws_size,
                              hipStream_t stream) {
    const int*   nb    = (const int*)d_in[0];     // [2*E]
    const float* areas = (const float*)d_in[1];   // [N]
    const float* dens  = (const float*)d_in[2];   // [N]
    const float* rest  = (const float*)d_in[3];   // [N]
    const float* q     = (const float*)d_in[4];   // [E]
    const float* dist  = (const float*)d_in[5];   // [E,2]
    float* out = (float*)d_out;                   // [N,2]

    // ws layout: [normals: 1 MB pad][partials: C * NP_PAD * 2 floats]
    const size_t normals_pad = 1 << 20;
    float* normals  = (float*)d_ws;
    float* partials = (float*)((char*)d_ws + normals_pad);

    const size_t per_chunk = (size_t)NP_PAD * 2 * sizeof(float);
    int C = 0;
    if (ws_size > normals_pad) {
        C = (int)((ws_size - normals_pad) / per_chunk);
        if (C > C_TARGET) C = C_TARGET;
    }

    if (C >= 4) {
        const int grid = NBINS * C;
        pass1_binned<<<grid, 1024, 0, stream>>>(
            nb, areas, dens, q, (const float2*)dist, partials, C);
        reduce_partials<<<(N_PART + 255) / 256, 256, 0, stream>>>(partials, normals, C);
        pass2_binned<<<grid, 1024, 0, stream>>>(
            nb, areas, rest, q, (const float2*)dist, (const float2*)normals, partials, C);
        reduce_partials<<<(N_PART + 255) / 256, 256, 0, stream>>>(partials, out, C);
    } else {
        // ws too small for partials: fall back to fabric-atomic path
        const int nv = 2 * N_PART;
        zero2_kernel<<<(nv + 255) / 256, 256, 0, stream>>>(normals, out, nv);
        const int blocks = (N_EDGE + 255) / 256;
        pass1_atomic<<<blocks, 256, 0, stream>>>(
            nb, areas, dens, q, (const float2*)dist, normals);
        pass2_atomic<<<blocks, 256, 0, stream>>>(
            nb, areas, rest, q, (const float2*)dist, (const float2*)normals, out);
    }
}